// Round 2
// baseline (599.223 us; speedup 1.0000x reference)
//
#include <hip/hip_runtime.h>
#include <hip/hip_bf16.h>
#include <stdint.h>

// ExpertScatter: out[b, Ind[b,e,k], i] += sum_j Y[b,e,k,j] * W[e,j,i]
// B=8 H=16 K=1024 D=128 I=1024 T=4096
#define B_ 8
#define H_ 16
#define K_ 1024
#define D_ 128
#define I_ 1024
#define T_ 4096

typedef __bf16 bf16x8 __attribute__((ext_vector_type(8)));
typedef unsigned short ushort8_t __attribute__((ext_vector_type(8)));
typedef unsigned short ushort4_t __attribute__((ext_vector_type(4)));
typedef float f32x4 __attribute__((ext_vector_type(4)));

__device__ __forceinline__ unsigned short f32_to_bf16_rne(float f) {
    union { float f; uint32_t u; } v; v.f = f;
    uint32_t u = v.u;
    u += 0x7FFFu + ((u >> 16) & 1u);   // round-to-nearest-even
    return (unsigned short)(u >> 16);
}

// ---------------------------------------------------------------- zero out
__global__ __launch_bounds__(256) void zero_out_kernel(float* __restrict__ p, int n4) {
    int i = blockIdx.x * 256 + threadIdx.x;
    int stride = gridDim.x * 256;
    f32x4 z = {0.f, 0.f, 0.f, 0.f};
    for (; i < n4; i += stride) ((f32x4*)p)[i] = z;
}

// ------------------------------------------------- W[e][j][i] -> Wt bf16 [e][i][j]
__global__ __launch_bounds__(256) void transpose_w_kernel(
    const float* __restrict__ W, unsigned short* __restrict__ Wt)
{
    int e  = blockIdx.x >> 6;            // 16 heads
    int i0 = (blockIdx.x & 63) << 4;     // 64 tiles of 16 cols
    int t  = threadIdx.x;
    int i  = i0 + (t & 15);
    int j8 = t >> 4;                     // 16 groups of 8 j's
    ushort8_t v;
    #pragma unroll
    for (int jj = 0; jj < 8; ++jj) {
        int j = j8 * 8 + jj;
        v[jj] = f32_to_bf16_rne(W[((size_t)e * D_ + j) * I_ + i]);
    }
    *(ushort8_t*)(Wt + ((size_t)e * I_ + i) * D_ + j8 * 8) = v;
}

// ---------------------------------------------------------------- main GEMM+scatter
// grid: 2048 blocks = b(8) x e(16) x mtile(16).  block: 256 thr = 4 waves.
// Per block: 64 rows of Y (bf16, LDS, XOR-swizzled) x full N=1024 in 4 chunks of 256.
// Wave w owns 64 cols of each chunk: 4x4 fragments of 16x16x32 bf16 MFMA.
// Epilogue: unsafeAtomicAdd into out[b, Ind[row], col].
template<bool USE_WT>
__global__ __launch_bounds__(256) void expert_mm_scatter_kernel(
    const float* __restrict__ Y, const int* __restrict__ Ind,
    const unsigned short* __restrict__ Wt, const float* __restrict__ Wf,
    float* __restrict__ out)
{
    __shared__ unsigned short Ylds[64 * 128];   // 16 KB bf16, swizzled
    __shared__ int tIdx[64];

    const int bid = blockIdx.x;
    const int mt = bid & 15;
    const int e  = (bid >> 4) & 15;
    const int b  = bid >> 8;
    const int m0 = mt << 6;

    const int tid = threadIdx.x;
    if (tid < 64) tIdx[tid] = Ind[((size_t)b * H_ + e) * K_ + m0 + tid];

    // stage Y tile -> bf16 LDS (swizzle byte ^= (row&7)<<4 to kill ds_read_b128 bank conflicts)
    const float* Ybase = Y + (((size_t)b * H_ + e) * K_ + m0) * D_;
    #pragma unroll
    for (int p = 0; p < 8; ++p) {
        int idx = tid + (p << 8);           // float4 index, 2048 total
        int r   = idx >> 5;                 // row 0..63
        int c4  = idx & 31;                 // which float4 in the row
        f32x4 v = *(const f32x4*)(Ybase + r * D_ + c4 * 4);
        ushort4_t h;
        h[0] = f32_to_bf16_rne(v[0]);
        h[1] = f32_to_bf16_rne(v[1]);
        h[2] = f32_to_bf16_rne(v[2]);
        h[3] = f32_to_bf16_rne(v[3]);
        int byteoff = (r << 8) + (c4 << 3);
        byteoff ^= (r & 7) << 4;
        *(ushort4_t*)((char*)Ylds + byteoff) = h;
    }
    __syncthreads();

    const int l  = tid & 63;
    const int w  = tid >> 6;       // wave 0..3
    const int lr = l & 15;         // fragment row/col lane index
    const int lk = l >> 4;         // k-group 0..3
    const int swz = (lr & 7) << 4; // row&7 == lr&7 (m*16 doesn't touch low 3 bits)

    float* outB = out + (size_t)b * T_ * I_;

    #pragma unroll
    for (int ci = 0; ci < 4; ++ci) {
        const int colbase = (ci << 8) + (w << 6);
        f32x4 acc[4][4];
        #pragma unroll
        for (int m = 0; m < 4; ++m)
            #pragma unroll
            for (int n = 0; n < 4; ++n)
                acc[m][n] = (f32x4){0.f, 0.f, 0.f, 0.f};

        #pragma unroll
        for (int kk = 0; kk < 4; ++kk) {
            bf16x8 a[4], bfr[4];
            #pragma unroll
            for (int m = 0; m < 4; ++m) {
                int off = (((m << 4) + lr) << 8) + (kk << 6) + (lk << 4);
                off ^= swz;
                a[m] = __builtin_bit_cast(bf16x8, *(const ushort8_t*)((const char*)Ylds + off));
            }
            #pragma unroll
            for (int n = 0; n < 4; ++n) {
                int col = colbase + (n << 4) + lr;
                if (USE_WT) {
                    bfr[n] = __builtin_bit_cast(bf16x8,
                        *(const ushort8_t*)(Wt + ((size_t)e * I_ + col) * D_ + (kk << 5) + (lk << 3)));
                } else {
                    ushort8_t u;
                    #pragma unroll
                    for (int q = 0; q < 8; ++q)
                        u[q] = f32_to_bf16_rne(Wf[((size_t)e * D_ + (kk << 5) + (lk << 3) + q) * I_ + col]);
                    bfr[n] = __builtin_bit_cast(bf16x8, u);
                }
            }
            #pragma unroll
            for (int m = 0; m < 4; ++m)
                #pragma unroll
                for (int n = 0; n < 4; ++n)
                    acc[m][n] = __builtin_amdgcn_mfma_f32_16x16x32_bf16(a[m], bfr[n], acc[m][n], 0, 0, 0);
        }

        // scatter epilogue: C/D layout col=lane&15, row=(lane>>4)*4+reg  [m89-verified]
        #pragma unroll
        for (int m = 0; m < 4; ++m) {
            #pragma unroll
            for (int r = 0; r < 4; ++r) {
                int row = (m << 4) + (lk << 2) + r;
                int t_slot = tIdx[row];
                float* orow = outB + (size_t)t_slot * I_ + colbase;
                #pragma unroll
                for (int n = 0; n < 4; ++n)
                    unsafeAtomicAdd(orow + (n << 4) + lr, acc[m][n][r]);
            }
        }
    }
}

extern "C" void kernel_launch(void* const* d_in, const int* in_sizes, int n_in,
                              void* d_out, int out_size, void* d_ws, size_t ws_size,
                              hipStream_t stream) {
    const float* Y   = (const float*)d_in[0];
    const int*   Ind = (const int*)d_in[1];
    const float* W   = (const float*)d_in[3];
    float* out = (float*)d_out;

    // out is poisoned before every launch: zero it (empty slots must be 0).
    zero_out_kernel<<<dim3(2048), dim3(256), 0, stream>>>(out, out_size / 4);

    const size_t wt_bytes = (size_t)H_ * I_ * D_ * sizeof(unsigned short);  // 4 MB
    if (ws_size >= wt_bytes) {
        unsigned short* Wt = (unsigned short*)d_ws;
        transpose_w_kernel<<<dim3(16 * 64), dim3(256), 0, stream>>>(W, Wt);
        expert_mm_scatter_kernel<true><<<dim3(B_ * H_ * 16), dim3(256), 0, stream>>>(Y, Ind, Wt, nullptr, out);
    } else {
        expert_mm_scatter_kernel<false><<<dim3(B_ * H_ * 16), dim3(256), 0, stream>>>(Y, Ind, nullptr, W, out);
    }
}

// Round 3
// 415.929 us; speedup vs baseline: 1.4407x; 1.4407x over previous
//
#include <hip/hip_runtime.h>
#include <hip/hip_bf16.h>
#include <stdint.h>

// ExpertScatter: out[b, Ind[b,e,k], i] += sum_j Y[b,e,k,j] * W[e,j,i]
// B=8 H=16 K=1024 D=128 I=1024 T=4096
// Strategy: inverted index over Ind; X = Y@W into ws (bf16); gather-reduce
// per (b,t) slot -> write-once output (no f32 atomics, no zero-fill of out).
#define B_ 8
#define H_ 16
#define K_ 1024
#define D_ 128
#define I_ 1024
#define T_ 4096

typedef __bf16 bf16x8 __attribute__((ext_vector_type(8)));
typedef unsigned short ushort8_t __attribute__((ext_vector_type(8)));
typedef unsigned short ushort4_t __attribute__((ext_vector_type(4)));
typedef float f32x4 __attribute__((ext_vector_type(4)));

__device__ __forceinline__ unsigned short f32_to_bf16_rne(float f) {
    union { float f; uint32_t u; } v; v.f = f;
    uint32_t u = v.u;
    u += 0x7FFFu + ((u >> 16) & 1u);   // round-to-nearest-even
    return (unsigned short)(u >> 16);
}
__device__ __forceinline__ float bf16u_to_f(unsigned short u) {
    union { uint32_t u; float f; } v; v.u = ((uint32_t)u) << 16; return v.f;
}

// ---------------------------------------------------------------- zero out (fallback path only)
__global__ __launch_bounds__(256) void zero_out_kernel(float* __restrict__ p, int n4) {
    int i = blockIdx.x * 256 + threadIdx.x;
    int stride = gridDim.x * 256;
    f32x4 z = {0.f, 0.f, 0.f, 0.f};
    for (; i < n4; i += stride) ((f32x4*)p)[i] = z;
}

// ------------------------------------------------- W[e][j][i] -> Wt bf16 [e][i][j]
__global__ __launch_bounds__(256) void transpose_w_kernel(
    const float* __restrict__ W, unsigned short* __restrict__ Wt)
{
    int e  = blockIdx.x >> 6;
    int i0 = (blockIdx.x & 63) << 4;
    int t  = threadIdx.x;
    int i  = i0 + (t & 15);
    int j8 = t >> 4;
    ushort8_t v;
    #pragma unroll
    for (int jj = 0; jj < 8; ++jj) {
        int j = j8 * 8 + jj;
        v[jj] = f32_to_bf16_rne(W[((size_t)e * D_ + j) * I_ + i]);
    }
    *(ushort8_t*)(Wt + ((size_t)e * I_ + i) * D_ + j8 * 8) = v;
}

// ---------------------------------------------------------------- inverted index
__global__ __launch_bounds__(256) void count_kernel(const int* __restrict__ Ind,
                                                    int* __restrict__ counts) {
    int i = blockIdx.x * 256 + threadIdx.x;
    if (i < B_ * H_ * K_) {
        int b = i >> 14;                  // 16384 entries per b
        atomicAdd(&counts[b * T_ + Ind[i]], 1);
    }
}

// one block per b: exclusive scan of 4096 counts -> offs; also copy to cursor
__global__ __launch_bounds__(256) void scan_kernel(const int* __restrict__ counts,
                                                   int* __restrict__ offs,
                                                   int* __restrict__ cursor) {
    __shared__ int part[256];
    int b = blockIdx.x;
    const int* c = counts + b * T_;
    int t0 = threadIdx.x * 16;
    int loc[16];
    int s = 0;
    #pragma unroll
    for (int j = 0; j < 16; ++j) { loc[j] = s; s += c[t0 + j]; }
    part[threadIdx.x] = s;
    __syncthreads();
    if (threadIdx.x == 0) {
        int run = 0;
        for (int i = 0; i < 256; ++i) { int v = part[i]; part[i] = run; run += v; }
    }
    __syncthreads();
    int base = part[threadIdx.x];
    #pragma unroll
    for (int j = 0; j < 16; ++j) {
        int v = base + loc[j];
        offs[b * T_ + t0 + j] = v;
        cursor[b * T_ + t0 + j] = v;
    }
}

__global__ __launch_bounds__(256) void fill_perm_kernel(const int* __restrict__ Ind,
                                                        int* __restrict__ cursor,
                                                        int* __restrict__ perm) {
    int i = blockIdx.x * 256 + threadIdx.x;
    if (i < B_ * H_ * K_) {
        int b = i >> 14;
        int t = Ind[i];
        int pos = atomicAdd(&cursor[b * T_ + t], 1);
        perm[(b << 14) + pos] = i & 16383;   // local row within b
    }
}

// ---------------------------------------------------------------- GEMM -> X (bf16)
// grid: nb*256 blocks (bl x e x mtile). Swapped-operand MFMA: acc regs hold 4
// consecutive i-columns per lane -> packed ushort4 stores.
__global__ __launch_bounds__(256) void gemm_x_kernel(
    const float* __restrict__ Y, const unsigned short* __restrict__ Wt,
    unsigned short* __restrict__ X, int b0)
{
    __shared__ unsigned short Ylds[64 * 128];   // 16 KB, XOR-swizzled

    const int bid = blockIdx.x;
    const int mt = bid & 15;
    const int e  = (bid >> 4) & 15;
    const int bl = bid >> 8;
    const int b  = b0 + bl;

    const int tid = threadIdx.x;
    const float* Ybase = Y + (((size_t)b * H_ + e) * K_ + mt * 64) * D_;
    #pragma unroll
    for (int p = 0; p < 8; ++p) {
        int idx = tid + (p << 8);
        int r   = idx >> 5;
        int c4  = idx & 31;
        f32x4 v = *(const f32x4*)(Ybase + r * D_ + c4 * 4);
        ushort4_t h;
        h[0] = f32_to_bf16_rne(v[0]);
        h[1] = f32_to_bf16_rne(v[1]);
        h[2] = f32_to_bf16_rne(v[2]);
        h[3] = f32_to_bf16_rne(v[3]);
        int byteoff = (r << 8) + (c4 << 3);
        byteoff ^= (r & 7) << 4;
        *(ushort4_t*)((char*)Ylds + byteoff) = h;
    }
    __syncthreads();

    const int l  = tid & 63;
    const int w  = tid >> 6;
    const int lr = l & 15;
    const int lk = l >> 4;
    const int swz = (lr & 7) << 4;

    unsigned short* Xrow0 = X + (((size_t)bl * H_ + e) * K_ + mt * 64) * I_;

    #pragma unroll
    for (int ci = 0; ci < 4; ++ci) {
        const int colbase = (ci << 8) + (w << 6);
        f32x4 acc[4][4];
        #pragma unroll
        for (int m = 0; m < 4; ++m)
            #pragma unroll
            for (int n = 0; n < 4; ++n)
                acc[m][n] = (f32x4){0.f, 0.f, 0.f, 0.f};

        #pragma unroll
        for (int kk = 0; kk < 4; ++kk) {
            bf16x8 a[4], bfr[4];
            #pragma unroll
            for (int m = 0; m < 4; ++m) {
                int off = (((m << 4) + lr) << 8) + (kk << 6) + (lk << 4);
                off ^= swz;
                a[m] = __builtin_bit_cast(bf16x8, *(const ushort8_t*)((const char*)Ylds + off));
            }
            #pragma unroll
            for (int n = 0; n < 4; ++n) {
                int col = colbase + (n << 4) + lr;
                bfr[n] = __builtin_bit_cast(bf16x8,
                    *(const ushort8_t*)(Wt + ((size_t)e * I_ + col) * D_ + (kk << 5) + (lk << 3)));
            }
            // swapped operands: D = Wt_frag x Y_frag  => D[row=i][col=k]
            #pragma unroll
            for (int m = 0; m < 4; ++m)
                #pragma unroll
                for (int n = 0; n < 4; ++n)
                    acc[m][n] = __builtin_amdgcn_mfma_f32_16x16x32_bf16(bfr[n], a[m], acc[m][n], 0, 0, 0);
        }

        // lane holds X[row = m*16+lr][i = colbase + n*16 + lk*4 + r], r=0..3
        #pragma unroll
        for (int m = 0; m < 4; ++m) {
            unsigned short* xr = Xrow0 + (size_t)(m * 16 + lr) * I_;
            #pragma unroll
            for (int n = 0; n < 4; ++n) {
                ushort4_t h;
                h[0] = f32_to_bf16_rne(acc[m][n][0]);
                h[1] = f32_to_bf16_rne(acc[m][n][1]);
                h[2] = f32_to_bf16_rne(acc[m][n][2]);
                h[3] = f32_to_bf16_rne(acc[m][n][3]);
                *(ushort4_t*)(xr + colbase + (n << 4) + (lk << 2)) = h;
            }
        }
    }
}

// ---------------------------------------------------------------- gather-reduce
// one wave per (b,t) slot: sum contributor X rows, write out row once.
__global__ __launch_bounds__(256) void gather_kernel(
    const unsigned short* __restrict__ X, const int* __restrict__ perm,
    const int* __restrict__ counts, const int* __restrict__ offs,
    float* __restrict__ out, int b0)
{
    const int w    = threadIdx.x >> 6;
    const int lane = threadIdx.x & 63;
    const int s    = blockIdx.x * 4 + w;    // local slot within chunk
    const int bl   = s >> 12;               // 4096 slots per b
    const int t    = s & 4095;
    const int b    = b0 + bl;

    const int cnt  = counts[b * T_ + t];
    const int base = offs[b * T_ + t];
    const int* pm  = perm + ((size_t)b << 14) + base;

    float acc[16];
    #pragma unroll
    for (int j = 0; j < 16; ++j) acc[j] = 0.f;

    const size_t laneoff = (size_t)lane * 16;
    int c = 0;
    for (; c + 2 <= cnt; c += 2) {
        int r0 = pm[c], r1 = pm[c + 1];
        const ushort8_t* p0 = (const ushort8_t*)(X + (((size_t)bl << 14) + r0) * I_ + laneoff);
        const ushort8_t* p1 = (const ushort8_t*)(X + (((size_t)bl << 14) + r1) * I_ + laneoff);
        ushort8_t a0 = p0[0], a1 = p0[1];
        ushort8_t b0v = p1[0], b1v = p1[1];
        #pragma unroll
        for (int j = 0; j < 8; ++j) {
            acc[j]     += bf16u_to_f(a0[j]) + bf16u_to_f(b0v[j]);
            acc[8 + j] += bf16u_to_f(a1[j]) + bf16u_to_f(b1v[j]);
        }
    }
    if (c < cnt) {
        int r0 = pm[c];
        const ushort8_t* p0 = (const ushort8_t*)(X + (((size_t)bl << 14) + r0) * I_ + laneoff);
        ushort8_t a0 = p0[0], a1 = p0[1];
        #pragma unroll
        for (int j = 0; j < 8; ++j) {
            acc[j]     += bf16u_to_f(a0[j]);
            acc[8 + j] += bf16u_to_f(a1[j]);
        }
    }

    float* op = out + ((size_t)b * T_ + t) * I_ + laneoff;
    #pragma unroll
    for (int q = 0; q < 4; ++q) {
        f32x4 v = { acc[q * 4 + 0], acc[q * 4 + 1], acc[q * 4 + 2], acc[q * 4 + 3] };
        *(f32x4*)(op + q * 4) = v;
    }
}

// ---------------------------------------------------------------- fallback (round-2 atomic path)
template<bool USE_WT>
__global__ __launch_bounds__(256) void expert_mm_scatter_kernel(
    const float* __restrict__ Y, const int* __restrict__ Ind,
    const unsigned short* __restrict__ Wt, const float* __restrict__ Wf,
    float* __restrict__ out)
{
    __shared__ unsigned short Ylds[64 * 128];
    __shared__ int tIdx[64];

    const int bid = blockIdx.x;
    const int mt = bid & 15;
    const int e  = (bid >> 4) & 15;
    const int b  = bid >> 8;
    const int m0 = mt << 6;

    const int tid = threadIdx.x;
    if (tid < 64) tIdx[tid] = Ind[((size_t)b * H_ + e) * K_ + m0 + tid];

    const float* Ybase = Y + (((size_t)b * H_ + e) * K_ + m0) * D_;
    #pragma unroll
    for (int p = 0; p < 8; ++p) {
        int idx = tid + (p << 8);
        int r   = idx >> 5;
        int c4  = idx & 31;
        f32x4 v = *(const f32x4*)(Ybase + r * D_ + c4 * 4);
        ushort4_t h;
        h[0] = f32_to_bf16_rne(v[0]);
        h[1] = f32_to_bf16_rne(v[1]);
        h[2] = f32_to_bf16_rne(v[2]);
        h[3] = f32_to_bf16_rne(v[3]);
        int byteoff = (r << 8) + (c4 << 3);
        byteoff ^= (r & 7) << 4;
        *(ushort4_t*)((char*)Ylds + byteoff) = h;
    }
    __syncthreads();

    const int l  = tid & 63;
    const int w  = tid >> 6;
    const int lr = l & 15;
    const int lk = l >> 4;
    const int swz = (lr & 7) << 4;

    float* outB = out + (size_t)b * T_ * I_;

    #pragma unroll
    for (int ci = 0; ci < 4; ++ci) {
        const int colbase = (ci << 8) + (w << 6);
        f32x4 acc[4][4];
        #pragma unroll
        for (int m = 0; m < 4; ++m)
            #pragma unroll
            for (int n = 0; n < 4; ++n)
                acc[m][n] = (f32x4){0.f, 0.f, 0.f, 0.f};

        #pragma unroll
        for (int kk = 0; kk < 4; ++kk) {
            bf16x8 a[4], bfr[4];
            #pragma unroll
            for (int m = 0; m < 4; ++m) {
                int off = (((m << 4) + lr) << 8) + (kk << 6) + (lk << 4);
                off ^= swz;
                a[m] = __builtin_bit_cast(bf16x8, *(const ushort8_t*)((const char*)Ylds + off));
            }
            #pragma unroll
            for (int n = 0; n < 4; ++n) {
                int col = colbase + (n << 4) + lr;
                if (USE_WT) {
                    bfr[n] = __builtin_bit_cast(bf16x8,
                        *(const ushort8_t*)(Wt + ((size_t)e * I_ + col) * D_ + (kk << 5) + (lk << 3)));
                } else {
                    ushort8_t u;
                    #pragma unroll
                    for (int q = 0; q < 8; ++q)
                        u[q] = f32_to_bf16_rne(Wf[((size_t)e * D_ + (kk << 5) + (lk << 3) + q) * I_ + col]);
                    bfr[n] = __builtin_bit_cast(bf16x8, u);
                }
            }
            #pragma unroll
            for (int m = 0; m < 4; ++m)
                #pragma unroll
                for (int n = 0; n < 4; ++n)
                    acc[m][n] = __builtin_amdgcn_mfma_f32_16x16x32_bf16(a[m], bfr[n], acc[m][n], 0, 0, 0);
        }

        #pragma unroll
        for (int m = 0; m < 4; ++m) {
            #pragma unroll
            for (int r = 0; r < 4; ++r) {
                int row = (m << 4) + (lk << 2) + r;
                int t_slot = tIdx[row];
                float* orow = outB + (size_t)t_slot * I_ + colbase;
                #pragma unroll
                for (int n = 0; n < 4; ++n)
                    unsafeAtomicAdd(orow + (n << 4) + lr, acc[m][n][r]);
            }
        }
    }
}

extern "C" void kernel_launch(void* const* d_in, const int* in_sizes, int n_in,
                              void* d_out, int out_size, void* d_ws, size_t ws_size,
                              hipStream_t stream) {
    const float* Y   = (const float*)d_in[0];
    const int*   Ind = (const int*)d_in[1];
    const float* W   = (const float*)d_in[3];
    float* out = (float*)d_out;
    char*  ws  = (char*)d_ws;

    const size_t WT_OFF   = 0;                       // 4 MB
    const size_t CNT_OFF  = (size_t)4 << 20;         // 128 KB
    const size_t OFF_OFF  = CNT_OFF + (128 << 10);   // 128 KB
    const size_t CUR_OFF  = OFF_OFF + (128 << 10);   // 128 KB
    const size_t PERM_OFF = CUR_OFF + (128 << 10);   // 512 KB
    const size_t X_OFF    = (size_t)5 << 20;
    const size_t XB       = (size_t)H_ * K_ * I_ * 2; // 32 MB per b

    int nb = 0;
    for (int cand = 8; cand >= 1; cand >>= 1)
        if (ws_size >= X_OFF + (size_t)cand * XB) { nb = cand; break; }

    if (nb) {
        unsigned short* Wt   = (unsigned short*)(ws + WT_OFF);
        int*  counts = (int*)(ws + CNT_OFF);
        int*  offs   = (int*)(ws + OFF_OFF);
        int*  cursor = (int*)(ws + CUR_OFF);
        int*  perm   = (int*)(ws + PERM_OFF);
        unsigned short* X = (unsigned short*)(ws + X_OFF);

        hipMemsetAsync(counts, 0, (size_t)B_ * T_ * sizeof(int), stream);
        transpose_w_kernel<<<dim3(1024), dim3(256), 0, stream>>>(W, Wt);
        count_kernel<<<dim3(512), dim3(256), 0, stream>>>(Ind, counts);
        scan_kernel<<<dim3(8), dim3(256), 0, stream>>>(counts, offs, cursor);
        fill_perm_kernel<<<dim3(512), dim3(256), 0, stream>>>(Ind, cursor, perm);
        for (int b0 = 0; b0 < B_; b0 += nb) {
            gemm_x_kernel<<<dim3(nb * 256), dim3(256), 0, stream>>>(Y, Wt, X, b0);
            gather_kernel<<<dim3(nb * 1024), dim3(256), 0, stream>>>(X, perm, counts, offs, out, b0);
        }
    } else {
        zero_out_kernel<<<dim3(2048), dim3(256), 0, stream>>>(out, out_size / 4);
        const size_t wt_bytes = (size_t)H_ * I_ * D_ * sizeof(unsigned short);
        if (ws_size >= wt_bytes) {
            unsigned short* Wt = (unsigned short*)d_ws;
            transpose_w_kernel<<<dim3(1024), dim3(256), 0, stream>>>(W, Wt);
            expert_mm_scatter_kernel<true><<<dim3(B_ * H_ * 16), dim3(256), 0, stream>>>(Y, Ind, Wt, nullptr, out);
        } else {
            expert_mm_scatter_kernel<false><<<dim3(B_ * H_ * 16), dim3(256), 0, stream>>>(Y, Ind, nullptr, W, out);
        }
    }
}

// Round 4
// 381.308 us; speedup vs baseline: 1.5715x; 1.0908x over previous
//
#include <hip/hip_runtime.h>
#include <hip/hip_bf16.h>
#include <stdint.h>

// ExpertScatter: out[b, Ind[b,e,k], i] += sum_j Y[b,e,k,j] * W[e,j,i]
// B=8 H=16 K=1024 D=128 I=1024 T=4096
// v4 pipeline: prep (Y->bf16 swizzled image, W->Wt swizzled image)
//            + index (count/scan/sortpos in one kernel)
//            + gemm  (one-shot global_load_lds staging, 128x128 tile, writes X slot-sorted)
//            + gather (contiguous per-slot reduce, write-once output)
#define B_ 8
#define H_ 16
#define K_ 1024
#define D_ 128
#define I_ 1024
#define T_ 4096
#define NROW_B (H_ * K_)   // 16384 rows per batch

typedef __bf16 bf16x8 __attribute__((ext_vector_type(8)));
typedef unsigned short ushort8_t __attribute__((ext_vector_type(8)));
typedef unsigned short ushort4_t __attribute__((ext_vector_type(4)));
typedef float f32x4 __attribute__((ext_vector_type(4)));

__device__ __forceinline__ unsigned short f32_to_bf16_rne(float f) {
    union { float f; uint32_t u; } v; v.f = f;
    uint32_t u = v.u;
    u += 0x7FFFu + ((u >> 16) & 1u);
    return (unsigned short)(u >> 16);
}
__device__ __forceinline__ float bf16u_to_f(unsigned short u) {
    union { uint32_t u; float f; } v; v.u = ((uint32_t)u) << 16; return v.f;
}

// async global->LDS, 16B per lane; lds must be wave-uniform, g is per-lane.
__device__ __forceinline__ void async_lds16(void* lds, const void* g) {
    __builtin_amdgcn_global_load_lds(
        (const __attribute__((address_space(1))) uint32_t*)g,
        (__attribute__((address_space(3))) uint32_t*)lds, 16, 0, 0);
}

// ---------------------------------------------------------------- prep:
// blocks [0,8192): Y fp32 -> Yb bf16 image, row-major 256B/row with
//   image[r*256 + cb] = logical[r][cb ^ ((r&7)<<4)]  (XOR-swizzle baked in)
// blocks [8192,9216): W[e][j][i] -> Wt image tiles [(e*8+cc)][ri][256B], same swizzle.
__global__ __launch_bounds__(256) void prep_kernel(
    const float* __restrict__ Y, const float* __restrict__ W,
    unsigned short* __restrict__ Yb, unsigned short* __restrict__ Wt)
{
    int bid = blockIdx.x;
    if (bid < 8192) {
        int chunk = bid * 256 + threadIdx.x;   // 16B chunk id
        int r  = chunk >> 4;                   // global row 0..131071
        int cb = (chunk & 15) << 4;            // image byte offset
        int kb = cb ^ ((r & 7) << 4);          // logical byte offset
        const float* src = Y + (size_t)r * D_ + (kb >> 1);
        f32x4 v0 = *(const f32x4*)src;
        f32x4 v1 = *(const f32x4*)(src + 4);
        ushort8_t h;
        h[0] = f32_to_bf16_rne(v0[0]); h[1] = f32_to_bf16_rne(v0[1]);
        h[2] = f32_to_bf16_rne(v0[2]); h[3] = f32_to_bf16_rne(v0[3]);
        h[4] = f32_to_bf16_rne(v1[0]); h[5] = f32_to_bf16_rne(v1[1]);
        h[6] = f32_to_bf16_rne(v1[2]); h[7] = f32_to_bf16_rne(v1[3]);
        *(ushort8_t*)((char*)Yb + (size_t)r * 256 + cb) = h;
    } else {
        int tb = bid - 8192;
        int e  = tb >> 6;
        int i0 = (tb & 63) << 4;
        int t  = threadIdx.x;
        int i  = i0 + (t & 15);
        int j8 = t >> 4;                       // k-chunk of 8
        ushort8_t v;
        #pragma unroll
        for (int jj = 0; jj < 8; ++jj)
            v[jj] = f32_to_bf16_rne(W[((size_t)e * D_ + j8 * 8 + jj) * I_ + i]);
        int cc = i >> 7, ri = i & 127;
        int cb = (j8 << 4) ^ ((ri & 7) << 4);
        *(ushort8_t*)((char*)Wt + ((size_t)(e * 8 + cc) * 128 + ri) * 256 + cb) = v;
    }
}

// ---------------------------------------------------------------- index:
// one block per b: LDS count -> exclusive scan -> sortpos (stable-ish rank).
__global__ __launch_bounds__(1024) void index_kernel(
    const int* __restrict__ Ind, int* __restrict__ counts,
    int* __restrict__ offs, int* __restrict__ sortpos)
{
    __shared__ int cnt_s[T_];
    __shared__ int off_s[T_];
    __shared__ int wsum[16], wbase[16];
    int b = blockIdx.x, tid = threadIdx.x;
    const int* ind = Ind + (size_t)b * NROW_B;
    #pragma unroll
    for (int j = 0; j < 4; ++j) cnt_s[tid + j * 1024] = 0;
    __syncthreads();
    #pragma unroll
    for (int j = 0; j < 16; ++j) atomicAdd(&cnt_s[ind[tid + j * 1024]], 1);
    __syncthreads();
    int t0 = tid * 4;
    int v0 = cnt_s[t0], v1 = cnt_s[t0 + 1], v2 = cnt_s[t0 + 2], v3 = cnt_s[t0 + 3];
    int s = v0 + v1 + v2 + v3;
    int lane = tid & 63, w = tid >> 6;
    int x = s;
    #pragma unroll
    for (int d = 1; d < 64; d <<= 1) { int y = __shfl_up(x, d); if (lane >= d) x += y; }
    if (lane == 63) wsum[w] = x;
    __syncthreads();
    if (tid < 16) {
        int ws = wsum[tid]; int xx = ws;
        #pragma unroll
        for (int d = 1; d < 16; d <<= 1) { int y = __shfl_up(xx, d); if (tid >= d) xx += y; }
        wbase[tid] = xx - ws;
    }
    __syncthreads();
    int base = wbase[w] + x - s;
    int o0 = base, o1 = o0 + v0, o2 = o1 + v1, o3 = o2 + v2;
    off_s[t0] = o0; off_s[t0 + 1] = o1; off_s[t0 + 2] = o2; off_s[t0 + 3] = o3;
    counts[b * T_ + t0] = v0; counts[b * T_ + t0 + 1] = v1;
    counts[b * T_ + t0 + 2] = v2; counts[b * T_ + t0 + 3] = v3;
    offs[b * T_ + t0] = o0; offs[b * T_ + t0 + 1] = o1;
    offs[b * T_ + t0 + 2] = o2; offs[b * T_ + t0 + 3] = o3;
    __syncthreads();
    #pragma unroll
    for (int j = 0; j < 16; ++j) {
        int i = tid + j * 1024;
        int pos = atomicAdd(&off_s[ind[i]], 1);
        sortpos[(size_t)b * NROW_B + i] = pos;
    }
}

// ---------------------------------------------------------------- gemm:
// grid nwg = nb*1024 blocks (XCD-chunk swizzled). Block: 128 rows x 128 cols,
// K=128 one-shot staged (A 32KB + B 32KB via global_load_lds w=16).
// 4 waves 2x2; wave: 64x64 via 4x4x4 mfma_16x16x32. Writes X slot-sorted (bf16).
__global__ __launch_bounds__(256) void gemm_x_kernel(
    const unsigned short* __restrict__ Yb, const unsigned short* __restrict__ Wt,
    const int* __restrict__ sortpos, unsigned short* __restrict__ Xs,
    int b0, int nwg)
{
    __shared__ char Al[32768];
    __shared__ char Bl[32768];
    __shared__ int sIdx[128];

    int bid = blockIdx.x;
    int q = nwg >> 3;
    int wid = (bid & 7) * q + (bid >> 3);   // XCD-chunked (nwg % 8 == 0)
    int cchunk = wid & 7;
    int rb = wid >> 3;
    int bl = rb >> 7;
    int em = rb & 127;
    int e  = em >> 3;
    int mt = em & 7;
    int b  = b0 + bl;

    int tid = threadIdx.x;
    int w = tid >> 6, l = tid & 63;

    size_t grow0 = (size_t)b * NROW_B + e * K_ + mt * 128;
    const char* Asrc = (const char*)Yb + grow0 * 256;
    const char* Bsrc = (const char*)Wt + ((size_t)(e * 8 + cchunk) * 128) * 256;
    {
        const char* ga = Asrc + w * 8192 + l * 16;
        const char* gb = Bsrc + w * 8192 + l * 16;
        char* la = Al + w * 8192;
        char* lb = Bl + w * 8192;
        #pragma unroll
        for (int p = 0; p < 8; ++p) {
            async_lds16(la + p * 1024, ga + p * 1024);
            async_lds16(lb + p * 1024, gb + p * 1024);
        }
    }
    if (tid < 128) sIdx[tid] = sortpos[grow0 + tid];
    __syncthreads();

    int wr = w >> 1, wc = w & 1;
    int lr = l & 15, lk = l >> 4;
    int swz = (lr & 7) << 4;

    f32x4 acc[4][4];
    #pragma unroll
    for (int m = 0; m < 4; ++m)
        #pragma unroll
        for (int n = 0; n < 4; ++n)
            acc[m][n] = (f32x4){0.f, 0.f, 0.f, 0.f};

    const char* Abase = Al + wr * 16384 + lr * 256;
    const char* Bbase = Bl + wc * 16384 + lr * 256;

    #pragma unroll
    for (int kk = 0; kk < 4; ++kk) {
        int koff = ((kk << 6) + (lk << 4)) ^ swz;
        bf16x8 af[4], bf[4];
        #pragma unroll
        for (int m = 0; m < 4; ++m)
            af[m] = __builtin_bit_cast(bf16x8, *(const ushort8_t*)(Abase + m * 4096 + koff));
        #pragma unroll
        for (int n = 0; n < 4; ++n)
            bf[n] = __builtin_bit_cast(bf16x8, *(const ushort8_t*)(Bbase + n * 4096 + koff));
        #pragma unroll
        for (int m = 0; m < 4; ++m)
            #pragma unroll
            for (int n = 0; n < 4; ++n)
                acc[m][n] = __builtin_amdgcn_mfma_f32_16x16x32_bf16(bf[n], af[m], acc[m][n], 0, 0, 0);
    }

    // D layout (swapped operands, verified r3): lane(lr,lk) holds
    // X[row = wr*64+m*16+lr][i = cchunk*128 + wc*64 + n*16 + lk*4 + q]
    unsigned short* Xbl = Xs + (size_t)bl * NROW_B * I_;
    int icolbase = cchunk * 128 + wc * 64 + (lk << 2);
    #pragma unroll
    for (int m = 0; m < 4; ++m) {
        int sp = sIdx[wr * 64 + m * 16 + lr];
        unsigned short* xr = Xbl + (size_t)sp * I_;
        #pragma unroll
        for (int n = 0; n < 4; ++n) {
            ushort4_t hq;
            hq[0] = f32_to_bf16_rne(acc[m][n][0]);
            hq[1] = f32_to_bf16_rne(acc[m][n][1]);
            hq[2] = f32_to_bf16_rne(acc[m][n][2]);
            hq[3] = f32_to_bf16_rne(acc[m][n][3]);
            *(ushort4_t*)(xr + icolbase + (n << 4)) = hq;
        }
    }
}

// ---------------------------------------------------------------- gather:
// wave per (b,t) slot; contributor rows are CONTIGUOUS [base, base+cnt).
__global__ __launch_bounds__(256) void gather_kernel(
    const unsigned short* __restrict__ Xs, const int* __restrict__ counts,
    const int* __restrict__ offs, float* __restrict__ out, int b0)
{
    int w = threadIdx.x >> 6, lane = threadIdx.x & 63;
    int s = blockIdx.x * 4 + w;
    int bl = s >> 12, t = s & 4095;
    int b = b0 + bl;
    int cnt  = counts[b * T_ + t];
    int base = offs[b * T_ + t];

    const char* rp = (const char*)(Xs + ((size_t)bl * NROW_B + base) * I_) + lane * 32;

    float acc[16];
    #pragma unroll
    for (int j = 0; j < 16; ++j) acc[j] = 0.f;

    int c = 0;
    for (; c + 4 <= cnt; c += 4) {
        ushort8_t u0[4], u1[4];
        #pragma unroll
        for (int j = 0; j < 4; ++j) {
            u0[j] = *(const ushort8_t*)(rp + j * 2048);
            u1[j] = *(const ushort8_t*)(rp + j * 2048 + 16);
        }
        #pragma unroll
        for (int j = 0; j < 4; ++j)
            #pragma unroll
            for (int q = 0; q < 8; ++q) {
                acc[q]     += bf16u_to_f(u0[j][q]);
                acc[8 + q] += bf16u_to_f(u1[j][q]);
            }
        rp += 4 * 2048;
    }
    for (; c < cnt; ++c) {
        ushort8_t u0 = *(const ushort8_t*)(rp);
        ushort8_t u1 = *(const ushort8_t*)(rp + 16);
        #pragma unroll
        for (int q = 0; q < 8; ++q) {
            acc[q]     += bf16u_to_f(u0[q]);
            acc[8 + q] += bf16u_to_f(u1[q]);
        }
        rp += 2048;
    }

    float* op = out + ((size_t)b * T_ + t) * I_ + lane * 16;
    #pragma unroll
    for (int q = 0; q < 4; ++q) {
        f32x4 v = { acc[q * 4 + 0], acc[q * 4 + 1], acc[q * 4 + 2], acc[q * 4 + 3] };
        *(f32x4*)(op + q * 4) = v;
    }
}

// ---------------------------------------------------------------- fallback (tiny ws): atomic path
__global__ __launch_bounds__(256) void zero_out_kernel(float* __restrict__ p, int n4) {
    int i = blockIdx.x * 256 + threadIdx.x;
    int stride = gridDim.x * 256;
    f32x4 z = {0.f, 0.f, 0.f, 0.f};
    for (; i < n4; i += stride) ((f32x4*)p)[i] = z;
}

__global__ __launch_bounds__(256) void fallback_scatter_kernel(
    const float* __restrict__ Y, const int* __restrict__ Ind,
    const float* __restrict__ Wf, float* __restrict__ out)
{
    __shared__ unsigned short Ylds[64 * 128];
    __shared__ int tIdx[64];
    const int bid = blockIdx.x;
    const int mt = bid & 15;
    const int e  = (bid >> 4) & 15;
    const int b  = bid >> 8;
    const int m0 = mt << 6;
    const int tid = threadIdx.x;
    if (tid < 64) tIdx[tid] = Ind[((size_t)b * H_ + e) * K_ + m0 + tid];
    const float* Ybase = Y + (((size_t)b * H_ + e) * K_ + m0) * D_;
    #pragma unroll
    for (int p = 0; p < 8; ++p) {
        int idx = tid + (p << 8);
        int r = idx >> 5, c4 = idx & 31;
        f32x4 v = *(const f32x4*)(Ybase + r * D_ + c4 * 4);
        ushort4_t h;
        h[0] = f32_to_bf16_rne(v[0]); h[1] = f32_to_bf16_rne(v[1]);
        h[2] = f32_to_bf16_rne(v[2]); h[3] = f32_to_bf16_rne(v[3]);
        int byteoff = ((r << 8) + (c4 << 3)) ^ ((r & 7) << 4);
        *(ushort4_t*)((char*)Ylds + byteoff) = h;
    }
    __syncthreads();
    const int l = tid & 63, w = tid >> 6;
    const int lr = l & 15, lk = l >> 4;
    const int swz = (lr & 7) << 4;
    float* outB = out + (size_t)b * T_ * I_;
    #pragma unroll
    for (int ci = 0; ci < 4; ++ci) {
        const int colbase = (ci << 8) + (w << 6);
        f32x4 acc[4][4];
        #pragma unroll
        for (int m = 0; m < 4; ++m)
            #pragma unroll
            for (int n = 0; n < 4; ++n)
                acc[m][n] = (f32x4){0.f, 0.f, 0.f, 0.f};
        #pragma unroll
        for (int kk = 0; kk < 4; ++kk) {
            bf16x8 a[4], bfr[4];
            #pragma unroll
            for (int m = 0; m < 4; ++m) {
                int off = ((((m << 4) + lr) << 8) + (kk << 6) + (lk << 4)) ^ swz;
                a[m] = __builtin_bit_cast(bf16x8, *(const ushort8_t*)((const char*)Ylds + off));
            }
            #pragma unroll
            for (int n = 0; n < 4; ++n) {
                int col = colbase + (n << 4) + lr;
                ushort8_t u;
                #pragma unroll
                for (int qq = 0; qq < 8; ++qq)
                    u[qq] = f32_to_bf16_rne(Wf[((size_t)e * D_ + (kk << 5) + (lk << 3) + qq) * I_ + col]);
                bfr[n] = __builtin_bit_cast(bf16x8, u);
            }
            #pragma unroll
            for (int m = 0; m < 4; ++m)
                #pragma unroll
                for (int n = 0; n < 4; ++n)
                    acc[m][n] = __builtin_amdgcn_mfma_f32_16x16x32_bf16(a[m], bfr[n], acc[m][n], 0, 0, 0);
        }
        #pragma unroll
        for (int m = 0; m < 4; ++m)
            #pragma unroll
            for (int r = 0; r < 4; ++r) {
                int row = (m << 4) + (lk << 2) + r;
                float* orow = outB + (size_t)tIdx[row] * I_ + colbase;
                #pragma unroll
                for (int n = 0; n < 4; ++n)
                    unsafeAtomicAdd(orow + (n << 4) + lr, acc[m][n][r]);
            }
    }
}

extern "C" void kernel_launch(void* const* d_in, const int* in_sizes, int n_in,
                              void* d_out, int out_size, void* d_ws, size_t ws_size,
                              hipStream_t stream) {
    const float* Y   = (const float*)d_in[0];
    const int*   Ind = (const int*)d_in[1];
    const float* W   = (const float*)d_in[3];
    float* out = (float*)d_out;
    char*  ws  = (char*)d_ws;

    const size_t WT_OFF  = 0;                        // 4 MB (Wt image)
    const size_t CNT_OFF = (size_t)4 << 20;          // 128 KB
    const size_t OFF_OFF = CNT_OFF + (128 << 10);    // 128 KB
    const size_t SP_OFF  = OFF_OFF + (128 << 10);    // 512 KB (sortpos)
    const size_t YB_OFF  = (size_t)5 << 20;          // 32 MB (Yb image)
    const size_t X_OFF   = (size_t)37 << 20;
    const size_t XB      = (size_t)NROW_B * I_ * 2;  // 32 MB per b

    int nb = 0;
    for (int cand = 8; cand >= 1; cand >>= 1)
        if (ws_size >= X_OFF + (size_t)cand * XB) { nb = cand; break; }

    if (nb) {
        unsigned short* Wt = (unsigned short*)(ws + WT_OFF);
        int* counts  = (int*)(ws + CNT_OFF);
        int* offs    = (int*)(ws + OFF_OFF);
        int* sortpos = (int*)(ws + SP_OFF);
        unsigned short* Yb = (unsigned short*)(ws + YB_OFF);
        unsigned short* Xs = (unsigned short*)(ws + X_OFF);

        prep_kernel<<<dim3(9216), dim3(256), 0, stream>>>(Y, W, Yb, Wt);
        index_kernel<<<dim3(8), dim3(1024), 0, stream>>>(Ind, counts, offs, sortpos);
        for (int b0 = 0; b0 < B_; b0 += nb) {
            int nwg = nb * 1024;
            gemm_x_kernel<<<dim3(nwg), dim3(256), 0, stream>>>(Yb, Wt, sortpos, Xs, b0, nwg);
            gather_kernel<<<dim3(nwg), dim3(256), 0, stream>>>(Xs, counts, offs, out, b0);
        }
    } else {
        zero_out_kernel<<<dim3(2048), dim3(256), 0, stream>>>(out, out_size / 4);
        fallback_scatter_kernel<<<dim3(B_ * H_ * 16), dim3(256), 0, stream>>>(Y, Ind, W, out);
    }
}